// Round 5
// baseline (186.970 us; speedup 1.0000x reference)
//
#include <hip/hip_runtime.h>

// WeightedDiceLoss on MI355X -- round 12: two barrier-free streaming kernels.
// R7-R11 post-mortem invariant: every LDS-ring variant lands at 1.3-2.2 TB/s
// with ALL pipes <=35% -- memory-level-parallelism limited (bytes in flight /
// latency), capped by 2 blocks/CU LDS residency and lockstep structure.
// Fix: drop LDS entirely.
//   k1: each wave computes the horizontal 31-box of whole image rows
//       (verified segment-sum + 17 shuffles), stores fp16 hrow to workspace.
//       Each row computed ONCE chip-wide (no halo recompute). Pure stream.
//   k2: wave owns (image, 128-col block, 32-row band). Vertical 31-box kept
//       in 2 registers, slides +-1 row via two 4-B half2 loads from hrow
//       (L3-resident: 33.5 MB). Center target re-read (L3 carries the whole
//       134 MB set -- R10/R11 FETCH ~= compulsory proves it). Input = HBM.
//       16 waves/CU, unrolled -> ~12 independent loads in flight per wave.
// Workspace: 33.5 MB fp16 hrow + 16 KB partials (this is what d_ws is for).
// Precision: fp16 hrow (values <= 31, err ~2^-11*16/row) validated by R11.
//
// input, target: (64,1,512,512) fp32. Output: scalar fp32.
// weight = 1 + 5*|box31(target) - target|; loss = 1 - (2*I+1)/(A+B+1).

#define BATCH 64
#define H     512
#define W     512
#define NROWS (BATCH * H)              // 32768 image-rows
#define K1_BLOCKS 2048                 // 8192 waves, 4 rows each
#define K1_WAVES  (K1_BLOCKS * 4)
#define RB    32                       // rows per k2 wave-task
#define K2_BLOCKS 1024                 // 4096 wave-tasks (64 b x 4 cb x 16 bands)

typedef _Float16 half8 __attribute__((ext_vector_type(8)));
typedef _Float16 half2v __attribute__((ext_vector_type(2)));

// ---------------------------------------------------------------------------
// k1: hrow[r][x] = sum_{dx=-15..15} tgt[r][x+dx] (zero col padding), fp16.
// One wave per image-row per iteration; 4 rows/wave, unroll 2.
// ---------------------------------------------------------------------------
__global__ __launch_bounds__(256) void hrow_kernel(const float* __restrict__ tgt,
                                                   _Float16* __restrict__ hbuf) {
    const int tid  = threadIdx.x;
    const int lane = tid & 63;
    const int wid  = blockIdx.x * 4 + (tid >> 6);   // 0..8191
    const int col0 = lane * 8;

    const float mL1 = (lane >= 1) ? 1.f : 0.f;
    const float mR1 = (lane <= 62) ? 1.f : 0.f;
    const float mL2 = (lane >= 2) ? 1.f : 0.f;
    const float mR2 = (lane <= 61) ? 1.f : 0.f;

    #pragma unroll 2
    for (int k = 0; k < 4; ++k) {
        const int r = wid + K1_WAVES * k;           // 0..32767, adjacent waves
        const float* trow = tgt + (size_t)r * W;    //   -> adjacent rows
        const float4 v0 = *(const float4*)(trow + col0);
        const float4 v1 = *(const float4*)(trow + col0 + 4);

        // horizontal 31-window (verified segment-sum, zero padding at edges)
        const float p1 = v0.x;
        const float p2 = p1 + v0.y;
        const float p3 = p2 + v0.z;
        const float p4 = p3 + v0.w;
        const float p5 = p4 + v1.x;
        const float p6 = p5 + v1.y;
        const float p7 = p6 + v1.z;
        const float s  = p7 + v1.w;
        const float f1 = s - p1, f2 = s - p2, f3 = s - p3, f4 = s - p4;
        const float f5 = s - p5, f6 = s - p6, f7 = s - p7;

        const float sL1 = __shfl_up(s, 1, 64);
        const float sR1 = __shfl_down(s, 1, 64);
        const float g1 = __shfl_up(f1, 2, 64);
        const float g2 = __shfl_up(f2, 2, 64);
        const float g3 = __shfl_up(f3, 2, 64);
        const float g4 = __shfl_up(f4, 2, 64);
        const float g5 = __shfl_up(f5, 2, 64);
        const float g6 = __shfl_up(f6, 2, 64);
        const float g7 = __shfl_up(f7, 2, 64);
        const float q1 = __shfl_down(p1, 2, 64);
        const float q2 = __shfl_down(p2, 2, 64);
        const float q3 = __shfl_down(p3, 2, 64);
        const float q4 = __shfl_down(p4, 2, 64);
        const float q5 = __shfl_down(p5, 2, 64);
        const float q6 = __shfl_down(p6, 2, 64);
        const float q7 = __shfl_down(p7, 2, 64);

        const float S3 = fmaf(mL1, sL1, fmaf(mR1, sR1, s));
        half8 hv;
        hv[0] = (_Float16)fmaf(mL2, g1, S3);
        hv[1] = (_Float16)fmaf(mL2, g2, fmaf(mR2, q1, S3));
        hv[2] = (_Float16)fmaf(mL2, g3, fmaf(mR2, q2, S3));
        hv[3] = (_Float16)fmaf(mL2, g4, fmaf(mR2, q3, S3));
        hv[4] = (_Float16)fmaf(mL2, g5, fmaf(mR2, q4, S3));
        hv[5] = (_Float16)fmaf(mL2, g6, fmaf(mR2, q5, S3));
        hv[6] = (_Float16)fmaf(mL2, g7, fmaf(mR2, q6, S3));
        hv[7] = (_Float16)fmaf(mR2, q7, S3);
        *(half8*)(hbuf + (size_t)r * W + col0) = hv;    // 16-B aligned
    }
}

// ---------------------------------------------------------------------------
// k2: vertical 31-box over hrow (registers, slide +-1) + weight + partials.
// wid -> (b, cb, band); lane owns 2 columns. No LDS in hot path, no barriers.
// ---------------------------------------------------------------------------
__global__ __launch_bounds__(256) void main_kernel(const float* __restrict__ tgt,
                                                   const float* __restrict__ inp,
                                                   const _Float16* __restrict__ hbuf,
                                                   float4* __restrict__ partials) {
    const int tid  = threadIdx.x;
    const int lane = tid & 63;
    const int wv   = tid >> 6;
    const int wid  = blockIdx.x * 4 + wv;    // 0..4095
    const int b     = wid >> 6;              // 64 tasks per image
    const int inner = wid & 63;
    const int cb    = inner & 3;             // 4 col-blocks of 128
    const int band  = inner >> 2;            // 16 bands of 32 rows
    const int r0    = band * RB;
    const int col   = cb * 128 + lane * 2;

    const float*    timg = tgt  + (size_t)b * H * W;
    const float*    iimg = inp  + (size_t)b * H * W;
    const _Float16* himg = hbuf + (size_t)b * H * W;

    // ---- init vertical box for row r0: hrow rows r0-15 .. r0+15 -----------
    // r0+15 <= 495 < H always; r0-15 < 0 only for band 0 -> start index j0.
    float box0 = 0.f, box1 = 0.f;
    const int j0 = (r0 == 0) ? 15 : 0;
    #pragma unroll 8
    for (int j = j0; j < 31; ++j) {
        const int row = r0 - 15 + j;
        const half2v hv = *(const half2v*)(himg + (size_t)row * W + col);
        box0 += (float)hv[0]; box1 += (float)hv[1];
    }

    const float inv = 1.0f / 961.0f;
    float aI = 0.f, aA = 0.f, aB = 0.f;

    #pragma unroll 4
    for (int st = 0; st < RB; ++st) {
        const int h = r0 + st;
        if (st > 0) {
            const int ra = h + 15;           // entering row (wave-uniform guard)
            const int rs = h - 16;           // leaving row
            if (ra < H) {
                const half2v hv = *(const half2v*)(himg + (size_t)ra * W + col);
                box0 += (float)hv[0]; box1 += (float)hv[1];
            }
            if (rs >= 0) {
                const half2v hv = *(const half2v*)(himg + (size_t)rs * W + col);
                box0 -= (float)hv[0]; box1 -= (float)hv[1];
            }
        }
        const float2 tv = *(const float2*)(timg + (size_t)h * W + col);
        const float2 iv = *(const float2*)(iimg + (size_t)h * W + col);
        const float w0 = fmaf(5.0f, fabsf(fmaf(box0, inv, -tv.x)), 1.0f);
        const float w1 = fmaf(5.0f, fabsf(fmaf(box1, inv, -tv.y)), 1.0f);
        const float tw0 = tv.x * w0, tw1 = tv.y * w1;
        aI = fmaf(iv.x, tw0, fmaf(iv.y, tw1, aI));
        aA = fmaf(iv.x, w0,  fmaf(iv.y, w1,  aA));
        aB += tw0 + tw1;
    }

    // ---- wave reduction (64 lanes) ----------------------------------------
    #pragma unroll
    for (int off = 32; off > 0; off >>= 1) {
        aI += __shfl_down(aI, off, 64);
        aA += __shfl_down(aA, off, 64);
        aB += __shfl_down(aB, off, 64);
    }
    __shared__ float sm[12];
    if (lane == 0) { sm[wv] = aI; sm[4 + wv] = aA; sm[8 + wv] = aB; }
    __syncthreads();
    if (tid == 0) {
        float4 o;
        o.x = sm[0] + sm[1] + sm[2] + sm[3];
        o.y = sm[4] + sm[5] + sm[6] + sm[7];
        o.z = sm[8] + sm[9] + sm[10] + sm[11];
        o.w = 0.f;
        partials[blockIdx.x] = o;
    }
}

// ---------------------------------------------------------------------------
// Reduce K2_BLOCKS (1024) partials + finalize. One block, 1024 threads.
// ---------------------------------------------------------------------------
__global__ __launch_bounds__(1024) void reduce_kernel(const float4* __restrict__ partials,
                                                      float* __restrict__ out) {
    const int tid = threadIdx.x;
    const float4 v = partials[tid];          // exactly 1024 entries
    float aI = v.x, aA = v.y, aB = v.z;
    #pragma unroll
    for (int off = 32; off > 0; off >>= 1) {
        aI += __shfl_down(aI, off, 64);
        aA += __shfl_down(aA, off, 64);
        aB += __shfl_down(aB, off, 64);
    }
    __shared__ float s[3][16];
    const int wvx = tid >> 6, ln = tid & 63;
    if (ln == 0) { s[0][wvx] = aI; s[1][wvx] = aA; s[2][wvx] = aB; }
    __syncthreads();
    if (tid == 0) {
        float I = 0.f, A = 0.f, Bv = 0.f;
        #pragma unroll
        for (int k = 0; k < 16; ++k) { I += s[0][k]; A += s[1][k]; Bv += s[2][k]; }
        out[0] = 1.0f - (2.0f * I + 1.0f) / (A + Bv + 1.0f);
    }
}

extern "C" void kernel_launch(void* const* d_in, const int* in_sizes, int n_in,
                              void* d_out, int out_size, void* d_ws, size_t ws_size,
                              hipStream_t stream) {
    const float* inp = (const float*)d_in[0];   // "input"
    const float* tgt = (const float*)d_in[1];   // "target"
    float* out = (float*)d_out;

    // workspace layout:
    //   [0, 33554432)              fp16 hrow buffer (64*512*512 * 2 B)
    //   [33554432, 33554432+16KB)  per-block partials (float4 x 1024)
    _Float16* hbuf = (_Float16*)d_ws;
    float4* partials = (float4*)((char*)d_ws + (size_t)NROWS * W * sizeof(_Float16));

    hrow_kernel<<<K1_BLOCKS, 256, 0, stream>>>(tgt, hbuf);
    main_kernel<<<K2_BLOCKS, 256, 0, stream>>>(tgt, inp, hbuf, partials);
    reduce_kernel<<<1, 1024, 0, stream>>>(partials, out);
}

// Round 7
// 174.970 us; speedup vs baseline: 1.0686x; 1.0686x over previous
//
#include <hip/hip_runtime.h>

// WeightedDiceLoss on MI355X -- round 14: resubmit of R13 (infra failure:
// Trio nursery ExceptionGroup, no kernel verdict). Design audit found no
// bounds/alignment/race faults; only change is trimming the bottom pad to
// the 15 rows actually read (HP 544 -> 543, ws 35.59 MB).
//
// R12 post-mortem smoking gun: main_kernel VGPR_Count = 28 -- the compiler
// did ZERO software pipelining because the hot-loop loads sat behind
// `if (ra < H)` / `if (rs >= 0)` guards (control flow blocks load hoisting).
// VALUBusy 11%, 1.75 TB/s: pure serial load-wait-use. Fixes:
//   * hrow workspace padded with 16 zero rows above / 15 below each image ->
//     EVERY hot-loop load unconditional; zeros fall out of the data.
//   * lane owns 8 cols -> all loads 16 B (half8 / float4).
//   * bands of 8 rows -> 4096 wave-tasks, 16 waves/CU; the 31-row box init
//     is a burst of 31 INDEPENDENT 16-B loads (ideal MLP), and the 4 waves
//     of a block cover overlapping init windows (L1/L2 reuse).
//   * nontemporal loads for single-use tgt/inp in k2 (preserve L2/L3 for
//     the reused hrow stream).
//   * k1: pure stream, no LDS, 4 rows/wave, full occupancy; also zeroes pads.
//
// input, target: (64,1,512,512) fp32. Output: scalar fp32.
// weight = 1 + 5*|box31(target) - target|; loss = 1 - (2*I+1)/(A+B+1).

#define BATCH 64
#define H     512
#define W     512
#define PADT  16                       // top zero rows (image rows -16..-1)
#define PADB  15                       // bottom zero rows (rows 512..526)
#define HP    (H + PADT + PADB)        // 543 padded hrow rows per image
#define K1_BLOCKS 2048                 // 8192 waves x 4 rows = 32768 rows
#define RB    8                        // rows per k2 wave-task
#define K2_BLOCKS 1024                 // 4096 wave-tasks: 64 img x 64 bands

typedef _Float16 half8  __attribute__((ext_vector_type(8)));
typedef float    floatx4 __attribute__((ext_vector_type(4)));

// ---------------------------------------------------------------------------
// k1: hrow[r][x] = sum_{dx=-15..15} tgt[r][x+dx] (zero col padding), fp16,
// stored at padded row (r&511)+PADT of image r>>9. Also zeroes the pad rows.
// ---------------------------------------------------------------------------
__global__ __launch_bounds__(256) void hrow_kernel(const float* __restrict__ tgt,
                                                   _Float16* __restrict__ hbuf) {
    const int tid  = threadIdx.x;
    const int lane = tid & 63;
    const int wid  = blockIdx.x * 4 + (tid >> 6);   // 0..8191
    const int col0 = lane * 8;

    const float mL1 = (lane >= 1) ? 1.f : 0.f;
    const float mR1 = (lane <= 62) ? 1.f : 0.f;
    const float mL2 = (lane >= 2) ? 1.f : 0.f;
    const float mR2 = (lane <= 61) ? 1.f : 0.f;

    // ---- zero the pad rows (16 top + 15 bottom per image; 31 per image) ---
    if (wid < BATCH * 32) {
        const int img = wid >> 5, p = wid & 31;     // p = 0..31
        if (p < 31) {
            const int row = (p < PADT) ? p : p + H; // [0,16) u [528,543)
            half8 z = {};
            *(half8*)(hbuf + ((size_t)img * HP + row) * W + col0) = z;
        }
    }

    #pragma unroll
    for (int k = 0; k < 4; ++k) {
        const int r = (wid << 2) + k;               // 0..32767
        const float* trow = tgt + (size_t)r * W;
        const floatx4 v0 = *(const floatx4*)(trow + col0);
        const floatx4 v1 = *(const floatx4*)(trow + col0 + 4);

        // horizontal 31-window (verified segment-sum, zero padding at edges)
        const float p1 = v0[0];
        const float p2 = p1 + v0[1];
        const float p3 = p2 + v0[2];
        const float p4 = p3 + v0[3];
        const float p5 = p4 + v1[0];
        const float p6 = p5 + v1[1];
        const float p7 = p6 + v1[2];
        const float s  = p7 + v1[3];
        const float f1 = s - p1, f2 = s - p2, f3 = s - p3, f4 = s - p4;
        const float f5 = s - p5, f6 = s - p6, f7 = s - p7;

        const float sL1 = __shfl_up(s, 1, 64);
        const float sR1 = __shfl_down(s, 1, 64);
        const float g1 = __shfl_up(f1, 2, 64);
        const float g2 = __shfl_up(f2, 2, 64);
        const float g3 = __shfl_up(f3, 2, 64);
        const float g4 = __shfl_up(f4, 2, 64);
        const float g5 = __shfl_up(f5, 2, 64);
        const float g6 = __shfl_up(f6, 2, 64);
        const float g7 = __shfl_up(f7, 2, 64);
        const float q1 = __shfl_down(p1, 2, 64);
        const float q2 = __shfl_down(p2, 2, 64);
        const float q3 = __shfl_down(p3, 2, 64);
        const float q4 = __shfl_down(p4, 2, 64);
        const float q5 = __shfl_down(p5, 2, 64);
        const float q6 = __shfl_down(p6, 2, 64);
        const float q7 = __shfl_down(p7, 2, 64);

        const float S3 = fmaf(mL1, sL1, fmaf(mR1, sR1, s));
        half8 hv;
        hv[0] = (_Float16)fmaf(mL2, g1, S3);
        hv[1] = (_Float16)fmaf(mL2, g2, fmaf(mR2, q1, S3));
        hv[2] = (_Float16)fmaf(mL2, g3, fmaf(mR2, q2, S3));
        hv[3] = (_Float16)fmaf(mL2, g4, fmaf(mR2, q3, S3));
        hv[4] = (_Float16)fmaf(mL2, g5, fmaf(mR2, q4, S3));
        hv[5] = (_Float16)fmaf(mL2, g6, fmaf(mR2, q5, S3));
        hv[6] = (_Float16)fmaf(mL2, g7, fmaf(mR2, q6, S3));
        hv[7] = (_Float16)fmaf(mR2, q7, S3);
        *(half8*)(hbuf + ((size_t)(r >> 9) * HP + (r & 511) + PADT) * W + col0) = hv;
    }
}

// ---------------------------------------------------------------------------
// k2: vertical 31-box over padded hrow (registers, slide +-1) + weight.
// Wave owns (image, 8-row band) at full width; lane owns 8 cols. ALL loads
// unconditional 16 B. No LDS in hot path, no barriers, XCD-swizzled.
// ---------------------------------------------------------------------------
__global__ __launch_bounds__(256, 4) void main_kernel(const float* __restrict__ tgt,
                                                      const float* __restrict__ inp,
                                                      const _Float16* __restrict__ hbuf,
                                                      float4* __restrict__ partials) {
    const int tid  = threadIdx.x;
    const int lane = tid & 63;
    const int wv   = tid >> 6;
    const int g    = blockIdx.x;
    const int blk  = ((g & 7) << 7) | (g >> 3);   // XCD-contiguous, bijective
    const int img  = blk >> 4;                    // 16 blocks per image
    const int band = (blk & 15) * 4 + wv;         // 0..63
    const int r0   = band * RB;
    const int col0 = lane * 8;

    const float*    timg = tgt  + (size_t)img * H * W;
    const float*    iimg = inp  + (size_t)img * H * W;
    const _Float16* hrp  = hbuf + (size_t)img * HP * W;   // padded base

    // ---- init box for h=r0: padded hrow rows r0+1 .. r0+31 ----------------
    // (image rows r0-15..r0+15; pads are zeros -> guard-free)
    float box[8];
    #pragma unroll
    for (int q = 0; q < 8; ++q) box[q] = 0.f;
    #pragma unroll
    for (int j = 0; j < 31; ++j) {
        const half8 hv = *(const half8*)(hrp + (size_t)(r0 + 1 + j) * W + col0);
        #pragma unroll
        for (int q = 0; q < 8; ++q) box[q] += (float)hv[q];
    }

    const float inv = 1.0f / 961.0f;
    float aI = 0.f, aA = 0.f, aB = 0.f;

    #pragma unroll
    for (int st = 0; st < RB; ++st) {
        const int h = r0 + st;
        // slide: += hrow[h+15] - hrow[h-16]  (padded rows h+31 / h; always
        // in-bounds <= 542 < 543, zero pads -> unconditional)
        if (st > 0) {                        // compile-time after full unroll
            const half8 a = *(const half8*)(hrp + (size_t)(h + 31) * W + col0);
            const half8 s = *(const half8*)(hrp + (size_t)h * W + col0);
            #pragma unroll
            for (int q = 0; q < 8; ++q) box[q] += (float)a[q] - (float)s[q];
        }
        // center rows: single-use -> nontemporal (keep L2/L3 for hrow)
        const floatx4 t0 = __builtin_nontemporal_load((const floatx4*)(timg + (size_t)h * W + col0));
        const floatx4 t1 = __builtin_nontemporal_load((const floatx4*)(timg + (size_t)h * W + col0 + 4));
        const floatx4 i0 = __builtin_nontemporal_load((const floatx4*)(iimg + (size_t)h * W + col0));
        const floatx4 i1 = __builtin_nontemporal_load((const floatx4*)(iimg + (size_t)h * W + col0 + 4));
        const float tv[8] = {t0[0], t0[1], t0[2], t0[3], t1[0], t1[1], t1[2], t1[3]};
        const float iv[8] = {i0[0], i0[1], i0[2], i0[3], i1[0], i1[1], i1[2], i1[3]};

        #pragma unroll
        for (int k = 0; k < 8; ++k) {
            const float wgt = fmaf(5.0f, fabsf(fmaf(box[k], inv, -tv[k])), 1.0f);
            const float tw  = tv[k] * wgt;
            aI = fmaf(iv[k], tw, aI);
            aA = fmaf(iv[k], wgt, aA);
            aB += tw;
        }
    }

    // ---- wave reduction (64 lanes) ----------------------------------------
    #pragma unroll
    for (int off = 32; off > 0; off >>= 1) {
        aI += __shfl_down(aI, off, 64);
        aA += __shfl_down(aA, off, 64);
        aB += __shfl_down(aB, off, 64);
    }
    __shared__ float sm[12];
    if (lane == 0) { sm[wv] = aI; sm[4 + wv] = aA; sm[8 + wv] = aB; }
    __syncthreads();
    if (tid == 0) {
        float4 o;
        o.x = sm[0] + sm[1] + sm[2] + sm[3];
        o.y = sm[4] + sm[5] + sm[6] + sm[7];
        o.z = sm[8] + sm[9] + sm[10] + sm[11];
        o.w = 0.f;
        partials[g] = o;
    }
}

// ---------------------------------------------------------------------------
// Reduce K2_BLOCKS (1024) partials + finalize. One block, 1024 threads.
// ---------------------------------------------------------------------------
__global__ __launch_bounds__(1024) void reduce_kernel(const float4* __restrict__ partials,
                                                      float* __restrict__ out) {
    const int tid = threadIdx.x;
    const float4 v = partials[tid];          // exactly 1024 entries
    float aI = v.x, aA = v.y, aB = v.z;
    #pragma unroll
    for (int off = 32; off > 0; off >>= 1) {
        aI += __shfl_down(aI, off, 64);
        aA += __shfl_down(aA, off, 64);
        aB += __shfl_down(aB, off, 64);
    }
    __shared__ float s[3][16];
    const int wvx = tid >> 6, ln = tid & 63;
    if (ln == 0) { s[0][wvx] = aI; s[1][wvx] = aA; s[2][wvx] = aB; }
    __syncthreads();
    if (tid == 0) {
        float I = 0.f, A = 0.f, Bv = 0.f;
        #pragma unroll
        for (int k = 0; k < 16; ++k) { I += s[0][k]; A += s[1][k]; Bv += s[2][k]; }
        out[0] = 1.0f - (2.0f * I + 1.0f) / (A + Bv + 1.0f);
    }
}

extern "C" void kernel_launch(void* const* d_in, const int* in_sizes, int n_in,
                              void* d_out, int out_size, void* d_ws, size_t ws_size,
                              hipStream_t stream) {
    const float* inp = (const float*)d_in[0];   // "input"
    const float* tgt = (const float*)d_in[1];   // "target"
    float* out = (float*)d_out;

    // workspace layout:
    //   [0, 35586048)            fp16 padded hrow (64 * 543 * 512 * 2 B)
    //   [35586048, +16 KB)       per-block partials (float4 x 1024)
    _Float16* hbuf = (_Float16*)d_ws;
    float4* partials = (float4*)((char*)d_ws + (size_t)BATCH * HP * W * sizeof(_Float16));

    hrow_kernel<<<K1_BLOCKS, 256, 0, stream>>>(tgt, hbuf);
    main_kernel<<<K2_BLOCKS, 256, 0, stream>>>(tgt, inp, hbuf, partials);
    reduce_kernel<<<1, 1024, 0, stream>>>(partials, out);
}